// Round 3
// baseline (221.704 us; speedup 1.0000x reference)
//
#include <hip/hip_runtime.h>
#include <stdint.h>

// CIN forward, MI355X. R10 = R9 (32x32x16 f16 MFMA) + two fixes driven by
// the R9 counters (MfmaUtil 53 at a 62us matrix floor, wall 151us):
//  1. Split-K accumulators acc[dt][s]: 4 independent MFMA chains (R9 had 2,
//     dep depth 4 -> matrix pipe starved on acc RAW latency). Partial sums
//     over the two k-slices of each channel, added once per layer.
//  2. HP 136->140: row stride 280B = 70 dw = 6 mod 32 -> 16 banks (2-way,
//     free) for hv/staging/writeback streams (was 8 banks / 4-way cost,
//     7.7M conflict cycles). xf one-time loads become b64 pairs (280 is
//     8B- but not 16B-aligned); hot-loop accesses unaffected.
// Wave = 1 o-tile(32) x 2 d-tiles, 4 waves/batch, 256-thr blocks, grid 1024
// (4 blocks/CU). Depth-2 consume-then-reload W rotation + hv double-buffer
// kept from R7/R9.

typedef __attribute__((ext_vector_type(8))) _Float16 f16x8;
typedef __attribute__((ext_vector_type(2))) _Float16 f16x2;
typedef __attribute__((ext_vector_type(4))) float f32x4;
typedef __attribute__((ext_vector_type(16))) float f32x16;
typedef __attribute__((ext_vector_type(4))) int i32x4;
typedef __attribute__((ext_vector_type(2))) int i32x2;

union AB {
  i32x4 i;
  f16x8 h;
  uint32_t u[4];
};
union AB2 {
  i32x2 i;
  uint32_t u[2];
};

static __device__ __forceinline__ uint32_t pkmul(uint32_t a, uint32_t b) {
  f16x2 r = __builtin_bit_cast(f16x2, a) * __builtin_bit_cast(f16x2, b);
  return __builtin_bit_cast(uint32_t, r);  // one v_pk_mul_f16
}
static __device__ __forceinline__ uint32_t pkcvt(float a, float b) {
  return __builtin_bit_cast(uint32_t, __builtin_amdgcn_cvt_pkrtz(a, b));
}

#define HP 140  // hT row: 128 ch + 12 pad (280B: 70 dw = 6 mod 32 -> 16 banks)

__global__ __launch_bounds__(256, 4) void cin_main(
    const float* __restrict__ x, const uint16_t* __restrict__ wp,
    const float* __restrict__ bias0, const float* __restrict__ bias1,
    const float* __restrict__ bias2, float* __restrict__ out) {
  __shared__ __align__(16) uint16_t hT[64][HP];  // [d][chan] fp16, one batch

  const int tid = threadIdx.x;
  const int ot = tid >> 6, lane = tid & 63;  // wave = o-tile index (0..3)
  const int hi = lane >> 5;   // A/B k-half; C row bit (4*hi)
  const int l31 = lane & 31;  // A row (o mod 32); B/C col (d mod 32)
  const int b = blockIdx.x;   // one batch per block

  // ---- stage x -> hT[d][m] fp16 (layer-0 h == x; 32 channels)
  for (int e = tid; e < 2048; e += 256) {
    int m = e >> 6, d = e & 63;
    hT[d][m] =
        __builtin_bit_cast(uint16_t, (_Float16)x[(size_t)b * 2048 + m * 64 + d]);
  }
  __syncthreads();

  // ---- x B-frags (loop-invariant): xf[dt][s].j = x[m=s*16+hi*8+j][d=dt*32+l31]
  // b64 pairs (row stride 280B is 8B-aligned, not 16B)
  AB xf[2][2];
#pragma unroll
  for (int dt = 0; dt < 2; ++dt)
#pragma unroll
    for (int s = 0; s < 2; ++s) {
      AB2 lo = *(const AB2*)&hT[dt * 32 + l31][s * 16 + hi * 8];
      AB2 hi4 = *(const AB2*)&hT[dt * 32 + l31][s * 16 + hi * 8 + 4];
      xf[dt][s].u[0] = lo.u[0];
      xf[dt][s].u[1] = lo.u[1];
      xf[dt][s].u[2] = hi4.u[0];
      xf[dt][s].u[3] = hi4.u[1];
    }

  f32x16 acc[2][2];  // [dt][s-parity] : 4 independent chains (split-K)

#pragma unroll
  for (int L = 0; L < 3; ++L) {
    const int Kch = (L == 0) ? 32 : 128;
    const uint16_t* wl = (L == 0) ? wp : (L == 1) ? wp + 131072 : wp + 655360;
    const float* bias = (L == 0) ? bias0 : (L == 1) ? bias1 : bias2;

    // packed W frag for (c,s): wl + ((ot*Kch + c)*2 + s)*512 + lane*8
    const uint16_t* wptr = wl + (size_t)ot * Kch * 1024 + lane * 8;

#pragma unroll
    for (int dt = 0; dt < 2; ++dt)
#pragma unroll
      for (int s = 0; s < 2; ++s)
#pragma unroll
        for (int r = 0; r < 16; ++r) acc[dt][s][r] = 0.f;

    AB wbuf[2][4];  // [slot][cc*2+s] : 32 VGPRs, depth-2 rotation
    uint32_t hvA[2], hvB[2];

    auto loadSlot = [&](int sl, int c) {
      int cw = (c < Kch) ? c : 0;  // wrap: harmless dummy reload
#pragma unroll
      for (int cc = 0; cc < 2; ++cc)
#pragma unroll
        for (int s = 0; s < 2; ++s)
          wbuf[sl][cc * 2 + s].i =
              *(const i32x4*)(wptr + (size_t)(cw + cc) * 1024 + s * 512);
    };
    auto loadHv = [&](uint32_t (&hv)[2], int c) {
      int cw = (c < Kch) ? c : 0;
#pragma unroll
      for (int dt = 0; dt < 2; ++dt)
        hv[dt] = *(const uint32_t*)&hT[dt * 32 + l31][cw];  // ch cw, cw+1
    };
    // one step = 2 channels (cc) x 2 k-slices (s) x 2 d-tiles = 8 MFMAs.
    // acc chain order per step: [0][0],[1][0],[0][1],[1][1] x2 -> RAW
    // distance 4 MFMAs (~128 pipe cycles).
    auto computeStep = [&](const AB (&wb)[4], const uint32_t (&hv)[2]) {
#pragma unroll
      for (int cc = 0; cc < 2; ++cc) {
        uint32_t hd0 = __builtin_amdgcn_perm(hv[0], hv[0],
                                             cc ? 0x03020302u : 0x01000100u);
        uint32_t hd1 = __builtin_amdgcn_perm(hv[1], hv[1],
                                             cc ? 0x03020302u : 0x01000100u);
#pragma unroll
        for (int s = 0; s < 2; ++s) {
          AB bf0, bf1;  // B: P[k=(c+cc)*32+s*16+hi*8+j][d] = h[c+cc,d]*x[m,d]
#pragma unroll
          for (int k = 0; k < 4; ++k) {
            bf0.u[k] = pkmul(hd0, xf[0][s].u[k]);
            bf1.u[k] = pkmul(hd1, xf[1][s].u[k]);
          }
          acc[0][s] = __builtin_amdgcn_mfma_f32_32x32x16_f16(
              wb[cc * 2 + s].h, bf0.h, acc[0][s], 0, 0, 0);
          acc[1][s] = __builtin_amdgcn_mfma_f32_32x32x16_f16(
              wb[cc * 2 + s].h, bf1.h, acc[1][s], 0, 0, 0);
        }
      }
    };

    // prologue: slots hold channel-pairs 0 and 2; hvA holds pair 0
    loadSlot(0, 0);
    loadSlot(1, 2);
    loadHv(hvA, 0);

#pragma unroll 1
    for (int c0 = 0; c0 < Kch; c0 += 4) {
      loadHv(hvB, c0 + 2);            // LDS prefetch for pair c0+2
      computeStep(wbuf[0], hvA);      // consume pair c0 ...
      loadSlot(0, c0 + 4);            // ... THEN reload slot 0 (pair c0+4)
      __builtin_amdgcn_sched_barrier(0);  // pin load issue here
      loadHv(hvA, c0 + 4);
      computeStep(wbuf[1], hvB);      // consume pair c0+2 ...
      loadSlot(1, c0 + 6);            // ... THEN reload slot 1 (pair c0+6)
      __builtin_amdgcn_sched_barrier(0);
    }

    // ---- merge split-K partials
    f32x16 a0, a1;
#pragma unroll
    for (int r = 0; r < 16; ++r) {
      a0[r] = acc[0][0][r] + acc[0][1][r];
      a1[r] = acc[1][0][r] + acc[1][1][r];
    }

    // ---- bias + ReLU. C layout (32x32): col d = dt*32 + l31,
    // row o = ot*32 + (r&3) + 8*(r>>2) + 4*hi
    f32x4 bv[4];
#pragma unroll
    for (int rg = 0; rg < 4; ++rg)
      bv[rg] = *(const f32x4*)(bias + ot * 32 + 8 * rg + 4 * hi);
#pragma unroll
    for (int r = 0; r < 16; ++r) {
      a0[r] = fmaxf(a0[r] + bv[r >> 2][r & 3], 0.f);
      a1[r] = fmaxf(a1[r] + bv[r >> 2][r & 3], 0.f);
    }

    if (L < 2) {
      __syncthreads();  // all waves done READING hT before overwrite
#pragma unroll
      for (int rg = 0; rg < 4; ++rg) {
        uint2 pk0, pk1;  // next-layer h channels, 4 consecutive rows
        pk0.x = pkcvt(a0[4 * rg + 0], a0[4 * rg + 1]);
        pk0.y = pkcvt(a0[4 * rg + 2], a0[4 * rg + 3]);
        pk1.x = pkcvt(a1[4 * rg + 0], a1[4 * rg + 1]);
        pk1.y = pkcvt(a1[4 * rg + 2], a1[4 * rg + 3]);
        int ch = ot * 32 + 8 * rg + 4 * hi;
        *(uint2*)&hT[l31][ch] = pk0;
        *(uint2*)&hT[32 + l31][ch] = pk1;
      }
    }

    // ---- d-sum: a0+a1 (d and d+32), then xor-reduce the 32 l31 lanes
#pragma unroll
    for (int rg = 0; rg < 4; ++rg) {
      f32x4 s4;
#pragma unroll
      for (int rr = 0; rr < 4; ++rr) {
        float s = a0[4 * rg + rr] + a1[4 * rg + rr];
        s += __shfl_xor(s, 1);
        s += __shfl_xor(s, 2);
        s += __shfl_xor(s, 4);
        s += __shfl_xor(s, 8);
        s += __shfl_xor(s, 16);
        s4[rr] = s;
      }
      if (l31 == 0)
        *(f32x4*)(out + (size_t)b * 384 + L * 128 + ot * 32 + 8 * rg + 4 * hi) = s4;
    }

    if (L < 2) __syncthreads();  // hT writes visible before next K-loop
  }
}

// Pack for 32x32x16 A layout: frag (ot,c,s) elem lane*8+j holds
// W[o = ot*32 + (lane&31)][k = c*32 + s*16 + (lane>>5)*8 + j].
// Reads stay coalesced along k (thread = (o,kq), 8 consecutive floats).
__global__ void pack_w_all(const float* __restrict__ W0, const float* __restrict__ W1,
                           const float* __restrict__ W2, uint16_t* __restrict__ Wp) {
  int blk = blockIdx.x;
  const float* W;
  uint16_t* dst;
  int kshift;  // Kch = 1<<kshift, K = 1<<(kshift+5)
  if (blk < 64)       { W = W0; dst = Wp;          kshift = 5; }
  else if (blk < 320) { W = W1; dst = Wp + 131072; kshift = 7; blk -= 64; }
  else                { W = W2; dst = Wp + 655360; kshift = 7; blk -= 320; }
  int idx = blk * 256 + threadIdx.x;
  int Kq = 1 << (kshift + 2);        // K/8
  int o = idx >> (kshift + 2);
  int kq = idx & (Kq - 1);
  int c = kq >> 2, s = (kq >> 1) & 1, hi = kq & 1;
  int ot = o >> 5, li = o & 31;
  const float* src = W + ((size_t)o << (kshift + 5)) + kq * 8;
  uint4 val;
  val.x = pkcvt(src[0], src[1]);
  val.y = pkcvt(src[2], src[3]);
  val.z = pkcvt(src[4], src[5]);
  val.w = pkcvt(src[6], src[7]);
  size_t d16 = ((((size_t)(ot << kshift) + c) * 2 + s) << 9) + (hi << 8) + (li << 3);
  *(uint4*)(dst + d16) = val;
}

extern "C" void kernel_launch(void* const* d_in, const int* in_sizes, int n_in,
                              void* d_out, int out_size, void* d_ws, size_t ws_size,
                              hipStream_t stream) {
  (void)in_sizes; (void)n_in; (void)out_size; (void)ws_size;
  const float* x  = (const float*)d_in[0];
  const float* W0 = (const float*)d_in[1];
  const float* b0 = (const float*)d_in[2];
  const float* W1 = (const float*)d_in[3];
  const float* b1 = (const float*)d_in[4];
  const float* W2 = (const float*)d_in[5];
  const float* b2 = (const float*)d_in[6];
  uint16_t* wpacked = (uint16_t*)d_ws;  // 2.25 MB of ws

  hipLaunchKernelGGL(pack_w_all, dim3(576), dim3(256), 0, stream, W0, W1, W2, wpacked);
  hipLaunchKernelGGL(cin_main, dim3(1024), dim3(256), 0, stream,
                     x, wpacked, b0, b1, b2, (float*)d_out);
}